// Round 15
// baseline (83.562 us; speedup 1.0000x reference)
//
#include <hip/hip_runtime.h>
#include <hip/hip_bf16.h>
#include <math.h>

// Sparsemax over rows of [N_ROWS, 64] fp32 — pair-per-row registers, LDS
// transpose buffer, ONE WAVE PER BLOCK (8KB private LDS).
//
// Ladder: r8 145us (scattered VMEM) -> r10 102.7 (coalesced granule+DPP) ->
// r12 84.6 (LDS transpose + register Michelot) -> r13 81.4 (no barriers, no
// result-write) -> r14 FAILED: max-fold's catastrophic cancellation amplified
// tau error to ~1e-5, flipping ~100 support boundaries (output jump 1/rho).
// LESSON: iteration arithmetic is FROZEN at r13's exact form (sub/max/add,
// same order). r15 = r13 arithmetic + block=64 only (pure scheduling).
//
// Michelot fixed point (z=1 simplex threshold), all decisions fp32
// (r6: fp16 flipped the support boundary -> 1/rho output jumps):
//   tau0 = max(x)-1 ; tau += (sum(max(0,x-tau))-1)/c ; stop when c fixed
//   (supports nested/shrinking; update idempotent at the fixed point).
//   reference's double -1: tau_out = tau* - 1/rho ; out = max(0, x - tau_out)

typedef float nfloat4 __attribute__((ext_vector_type(4)));

#define FOR8(OP) OP(0) OP(1) OP(2) OP(3) OP(4) OP(5) OP(6) OP(7)

__device__ __forceinline__ nfloat4 v4max(nfloat4 a, nfloat4 b) {
    nfloat4 r;
    r.x = fmaxf(a.x, b.x); r.y = fmaxf(a.y, b.y);
    r.z = fmaxf(a.z, b.z); r.w = fmaxf(a.w, b.w);
    return r;
}

__global__ __launch_bounds__(64) void sparsemax_w64(
    const float* __restrict__ x, float* __restrict__ out, long long n_rows) {
    __shared__ nfloat4 W[512];                    // 8 KB, wave-private
    const int lane = threadIdx.x;                 // block == one wave
    const long long row0 = (long long)blockIdx.x * 32;   // 32 rows per wave
    if (row0 >= n_rows) return;

    const nfloat4* __restrict__ xv = reinterpret_cast<const nfloat4*>(x);
    nfloat4* __restrict__ ov = reinterpret_cast<nfloat4*>(out);
    const long long gbase = row0 * 16;            // f4 index of tile
    const long long f4max = n_rows * 16;

    const bool full = (row0 + 32) <= n_rows;
    const int hi4 = lane >> 4;
    const int l15 = lane & 15;

    // ---- stage in: global coalesced -> LDS swizzled (conflict-free) ----
    if (full) {
#pragma unroll
        for (int i = 0; i < 8; ++i) {
            const int r = i * 4 + hi4;
            W[r * 16 + (l15 ^ (r & 7))] = xv[gbase + i * 64 + lane];
        }
    } else {
#pragma unroll
        for (int i = 0; i < 8; ++i) {
            const int r = i * 4 + hi4;
            nfloat4 t = {0.f, 0.f, 0.f, 0.f};
            if (gbase + i * 64 + lane < f4max) t = xv[gbase + i * 64 + lane];
            W[r * 16 + (l15 ^ (r & 7))] = t;
        }
    }
    asm volatile("" ::: "memory");   // phase order: writes before pair-reads

    const int prow = lane >> 1;                   // tile-local row of this pair
    const int s7 = prow & 7;
    const int pbase = prow * 16 + (lane & 1) * 8; // this lane's half-row base

    // ---- pair-read: half-row (32 floats) into pinned registers ----
#define PR(j) nfloat4 v##j = W[pbase + (j ^ s7)];
    FOR8(PR)
#undef PR
#define PIN(j) asm volatile("" : "+v"(v##j.x), "+v"(v##j.y), "+v"(v##j.z), "+v"(v##j.w));
    FOR8(PIN)
#undef PIN

    // ---- row max (local 31 + 1 pair-combine) -> tau0 = max - 1 ----
    nfloat4 m4 = v4max(v4max(v4max(v0, v1), v4max(v2, v3)),
                       v4max(v4max(v4, v5), v4max(v6, v7)));
    float m = fmaxf(fmaxf(m4.x, m4.y), fmaxf(m4.z, m4.w));
    m = fmaxf(m, __shfl_xor(m, 1, 64));

    float tau = m - 1.0f;
    int cprev = -1;                 // force at least one iteration
    float rfin = 1.0f;
    for (int it = 0; it < 40; ++it) {
        // FROZEN r13 arithmetic: s = sum(max(x - tau, 0)), same order
        float s0 = 0.f, s1 = 0.f;
        int c0 = 0, c1 = 0;
#define ACC(j) {                                              \
        const float d0 = v##j.x - tau, d1 = v##j.y - tau;     \
        const float d2 = v##j.z - tau, d3 = v##j.w - tau;     \
        s0 += fmaxf(d0, 0.f); c0 += (d0 > 0.f);               \
        s1 += fmaxf(d1, 0.f); c1 += (d1 > 0.f);               \
        s0 += fmaxf(d2, 0.f); c0 += (d2 > 0.f);               \
        s1 += fmaxf(d3, 0.f); c1 += (d3 > 0.f); }
        FOR8(ACC)
#undef ACC
        float s = s0 + s1;
        int c = c0 + c1;
        // pair combine (DPP quad_perm; commutative -> identical in pair)
        s += __shfl_xor(s, 1, 64);
        c += __shfl_xor(c, 1, 64);
        const bool done = (c == cprev);   // nested supports: count fixed
        cprev = c;
        const float rr = __builtin_amdgcn_rcpf((float)c);
        rfin = rr;
        tau += (s - 1.0f) * rr;           // idempotent once converged
        if (__all(done)) break;
    }
    const float tau_out = tau - rfin;     // reference double -1: tau* - 1/rho

    asm volatile("" ::: "memory");   // phase order: reads of originals below

    // ---- stage out: originals from LDS + tau via shfl -> coalesced NT store ----
    if (full) {
#pragma unroll
        for (int i = 0; i < 8; ++i) {
            const int r = i * 4 + hi4;
            const float tr = __shfl(tau_out, 8 * i + 2 * hi4, 64);
            const nfloat4 v = W[r * 16 + (l15 ^ (r & 7))];
            nfloat4 t;
            t.x = fmaxf(0.f, v.x - tr);
            t.y = fmaxf(0.f, v.y - tr);
            t.z = fmaxf(0.f, v.z - tr);
            t.w = fmaxf(0.f, v.w - tr);
            __builtin_nontemporal_store(t, &ov[gbase + i * 64 + lane]);
        }
    } else {
#pragma unroll
        for (int i = 0; i < 8; ++i) {
            const int r = i * 4 + hi4;
            const float tr = __shfl(tau_out, 8 * i + 2 * hi4, 64);
            const nfloat4 v = W[r * 16 + (l15 ^ (r & 7))];
            nfloat4 t;
            t.x = fmaxf(0.f, v.x - tr);
            t.y = fmaxf(0.f, v.y - tr);
            t.z = fmaxf(0.f, v.z - tr);
            t.w = fmaxf(0.f, v.w - tr);
            if (gbase + i * 64 + lane < f4max)
                __builtin_nontemporal_store(t, &ov[gbase + i * 64 + lane]);
        }
    }
}

extern "C" void kernel_launch(void* const* d_in, const int* in_sizes, int n_in,
                              void* d_out, int out_size, void* d_ws, size_t ws_size,
                              hipStream_t stream) {
    const float* x = (const float*)d_in[0];
    float* out = (float*)d_out;
    const long long n_rows = in_sizes[0] / 64;

    const int block = 64;                         // one wave per block
    const long long grid = (n_rows + 31) / 32;    // 32768 for 1M rows
    sparsemax_w64<<<(int)grid, block, 0, stream>>>(x, out, n_rows);
}